// Round 5
// baseline (154.070 us; speedup 1.0000x reference)
//
#include <hip/hip_runtime.h>
#include <hip/hip_bf16.h>

// Hmoe: gate = sigmoid(x @ w + b); tree-product over 6 levels -> P (32768 x 64);
// out = P @ responses.
// Kernel 0 (prep): w -> wTh/wTl bf16 [64][2048] hi/lo split; responses ->
//   RTs bf16 in MFMA-fragment order (contiguous 512B per wave B-fragment).
// Kernel 1 (fused): per 32-row block:
//   phase 1: gate GEMM, LDS-staged x/w per K-step, reg-prefetch (R4 structure)
//   phase 2: sigmoid -> gl; tree -> P tile bf16 in LDS (overlays xs)
//   phase 3: out rows = P_tile @ RT, B-frags straight from RTs (L2, coalesced,
//            fragment-ordered), A-frags in regs, ZERO barriers, stream stores.

typedef short bf16x8 __attribute__((ext_vector_type(8)));
typedef float f32x4  __attribute__((ext_vector_type(4)));

#define BS    32768
#define DIMX  2048
#define NODES 63
#define NL    64
#define DIMY  2048

__device__ __forceinline__ unsigned short f2bf(float f) {
    union { float f; unsigned int u; } v; v.f = f;
    unsigned int r = v.u + 0x7FFFu + ((v.u >> 16) & 1u);   // RNE
    return (unsigned short)(r >> 16);
}
__device__ __forceinline__ float bf2f(unsigned short h) {
    union { float f; unsigned int u; } v; v.u = ((unsigned int)h) << 16;
    return v.f;
}

// ---------------- kernel 0: prep (w split + responses fragment-swizzle) ------
// RTs layout: frag index g = nf*2 + kh  (nf: 16-col group 0..127, kh: k-half),
// element (g, lane l, e 0..7) = responses[k][n], k = kh*32+(l>>4)*8+e,
// n = nf*16+(l&15).  One wave B-frag load = RTs + g*512 + l*8 (contiguous).
__global__ __launch_bounds__(256) void prep(const float* __restrict__ w,
                                            const float* __restrict__ R,
                                            unsigned short* __restrict__ wTh,
                                            unsigned short* __restrict__ wTl,
                                            unsigned short* __restrict__ RTs) {
    int bid = blockIdx.x;
    int f = (bid & 511) * 256 + threadIdx.x;    // 0..131071
    if (bid < 512) {
        int n = f >> 11;                        // node 0..63
        int k = f & 2047;
        float v = (n < NODES) ? w[(size_t)k * NODES + n] : 0.0f;
        unsigned short h = f2bf(v);
        wTh[f] = h;
        wTl[f] = f2bf(v - bf2f(h));
    } else {
        int e  = f & 7;
        int l  = (f >> 3) & 63;
        int kh = (f >> 9) & 1;
        int nf = f >> 10;                       // 0..127
        int k  = kh * 32 + (l >> 4) * 8 + e;    // leaf index 0..63
        int n  = nf * 16 + (l & 15);            // dimy col
        RTs[f] = f2bf(R[(size_t)k * DIMY + n]);
    }
}

// ---------------- kernel 1: fused gates + tree + out -------------------------
#define GBM   32
#define GBK   64
#define GLD   72                    // padded LDS row stride (bf16): 144 B
#define NSTEP (DIMX / GBK)          // 32

__device__ __forceinline__ bf16x8 pack8(float4 a, float4 b) {
    union { __hip_bfloat162 h2[4]; bf16x8 v; } u;
    u.h2[0] = __float22bfloat162_rn(make_float2(a.x, a.y));
    u.h2[1] = __float22bfloat162_rn(make_float2(a.z, a.w));
    u.h2[2] = __float22bfloat162_rn(make_float2(b.x, b.y));
    u.h2[3] = __float22bfloat162_rn(make_float2(b.z, b.w));
    return u.v;
}

__global__ __launch_bounds__(256, 4) void fused_kernel(const float* __restrict__ x,
                                                       const unsigned short* __restrict__ wTh,
                                                       const unsigned short* __restrict__ wTl,
                                                       const float* __restrict__ bias,
                                                       const unsigned short* __restrict__ RTs,
                                                       float* __restrict__ out) {
    __shared__ __align__(16) unsigned short xs[GBM][GLD];   // phase1: x tile / phase3: P tile
    __shared__ __align__(16) unsigned short wsh[NL][GLD];
    __shared__ __align__(16) unsigned short wsl[NL][GLD];
    __shared__ float gl[GBM][NL + 1];

    const int t    = threadIdx.x;
    const int lane = t & 63;
    const int wv   = t >> 6;        // 4 waves
    const int lr   = lane & 15;
    const int lg   = lane >> 4;
    const int m0   = blockIdx.x * GBM;
    const int rm   = wv & 1;        // row-frag half (16 rows)
    const int cfp  = wv >> 1;       // col-frag pair (32 cols)

    // ---- phase 1: gate GEMM ----
    const int xr = t >> 3;
    const int xc = (t & 7) * 8;
    const float* xsrc = x + (size_t)(m0 + xr) * DIMX + xc;
    const int wrA = t >> 3;
    const int wrB = wrA + 32;
    const int wc  = (t & 7) * 8;
    const unsigned short* hA = wTh + (size_t)wrA * DIMX + wc;
    const unsigned short* hB = wTh + (size_t)wrB * DIMX + wc;
    const unsigned short* lA = wTl + (size_t)wrA * DIMX + wc;
    const unsigned short* lB = wTl + (size_t)wrB * DIMX + wc;

    float4 rx0 = *(const float4*)(xsrc);
    float4 rx1 = *(const float4*)(xsrc + 4);
    uint4  rhA = *(const uint4*)(hA);
    uint4  rhB = *(const uint4*)(hB);
    uint4  rlA = *(const uint4*)(lA);
    uint4  rlB = *(const uint4*)(lB);

    f32x4 acc[2];
    acc[0] = (f32x4){0.f, 0.f, 0.f, 0.f};
    acc[1] = (f32x4){0.f, 0.f, 0.f, 0.f};

    for (int k = 0; k < NSTEP; ++k) {
        __syncthreads();
        *(bf16x8*)&xs[xr][xc]  = pack8(rx0, rx1);
        *(uint4*)&wsh[wrA][wc] = rhA;
        *(uint4*)&wsh[wrB][wc] = rhB;
        *(uint4*)&wsl[wrA][wc] = rlA;
        *(uint4*)&wsl[wrB][wc] = rlB;
        __syncthreads();
        if (k + 1 < NSTEP) {
            const int ko = (k + 1) * GBK;
            rx0 = *(const float4*)(xsrc + ko);
            rx1 = *(const float4*)(xsrc + ko + 4);
            rhA = *(const uint4*)(hA + ko);
            rhB = *(const uint4*)(hB + ko);
            rlA = *(const uint4*)(lA + ko);
            rlB = *(const uint4*)(lB + ko);
        }
        #pragma unroll
        for (int kk = 0; kk < GBK; kk += 32) {
            bf16x8 a = *(const bf16x8*)&xs[rm * 16 + lr][kk + lg * 8];
            #pragma unroll
            for (int ci = 0; ci < 2; ++ci) {
                const int brow = (cfp * 2 + ci) * 16 + lr;
                bf16x8 bh = *(const bf16x8*)&wsh[brow][kk + lg * 8];
                bf16x8 bo = *(const bf16x8*)&wsl[brow][kk + lg * 8];
                acc[ci] = __builtin_amdgcn_mfma_f32_16x16x32_bf16(a, bh, acc[ci], 0, 0, 0);
                acc[ci] = __builtin_amdgcn_mfma_f32_16x16x32_bf16(a, bo, acc[ci], 0, 0, 0);
            }
        }
    }

    // ---- phase 2: bias + sigmoid -> gl; tree -> P tile (overlays xs) ----
    #pragma unroll
    for (int ci = 0; ci < 2; ++ci) {
        const int col = cfp * 32 + ci * 16 + lr;
        const float bb = bias[col < NODES ? col : 0];   // col 63 unread by tree
        #pragma unroll
        for (int i = 0; i < 4; ++i) {
            int row = rm * 16 + lg * 4 + i;
            float s = acc[ci][i] + bb;
            gl[row][col] = 1.0f / (1.0f + __expf(-s));
        }
    }
    __syncthreads();                  // gl visible; all xs reads done

    {
        const int rr  = t >> 3;       // 0..31
        const int sub = t & 7;
        const int b5 = sub & 1, b4 = (sub >> 1) & 1, mh = sub >> 2;
        const float* g = gl[rr];
        float a2[2], a4[4], a8[8];
        float g0 = g[0];
        a2[0] = g0; a2[1] = 1.f - g0;
        #pragma unroll
        for (int m = 0; m < 4; ++m) {
            float gg = g[1 + (m & 1)];
            a4[m] = a2[m & 1] * ((m & 2) ? (1.f - gg) : gg);
        }
        #pragma unroll
        for (int m = 0; m < 8; ++m) {
            float gg = g[3 + (m & 3)];
            a8[m] = a4[m & 3] * ((m & 4) ? (1.f - gg) : gg);
        }
        unsigned short o[8];
        #pragma unroll
        for (int j = 0; j < 8; ++j) {
            int m = mh * 8 + j;
            float g4 = g[7 + j];
            float p  = a8[j] * (mh ? (1.f - g4) : g4);
            float g5 = g[15 + m];
            p *= b4 ? (1.f - g5) : g5;
            float g6 = g[31 + m + 16 * b4];
            p *= b5 ? (1.f - g6) : g6;
            o[j] = f2bf(p);
        }
        uint4 q;
        q.x = (unsigned)o[0] | ((unsigned)o[1] << 16);
        q.y = (unsigned)o[2] | ((unsigned)o[3] << 16);
        q.z = (unsigned)o[4] | ((unsigned)o[5] << 16);
        q.w = (unsigned)o[6] | ((unsigned)o[7] << 16);
        *(uint4*)&xs[rr][b5 * 32 + b4 * 16 + mh * 8] = q;   // P tile
    }
    __syncthreads();                  // P tile visible

    // ---- phase 3: out rows = P_tile @ RT, no barriers ----
    bf16x8 pa[2][2];
    #pragma unroll
    for (int rf = 0; rf < 2; ++rf)
        #pragma unroll
        for (int kh = 0; kh < 2; ++kh)
            pa[rf][kh] = *(const bf16x8*)&xs[rf * 16 + lr][kh * 32 + lg * 8];

    const unsigned short* bbase = RTs + (size_t)(wv * 4) * 512 + (size_t)lane * 8;
    #define BLD(s, ci, kh) (*(const bf16x8*)(bbase + (size_t)(((s) * 16 + (ci) * 2 + (kh))) * 512))

    bf16x8 cur[4], nxt[4];
    cur[0] = BLD(0, 0, 0); cur[1] = BLD(0, 0, 1);
    cur[2] = BLD(0, 1, 0); cur[3] = BLD(0, 1, 1);

    float* op = out + (size_t)(m0 + lg * 4) * DIMY + wv * 32 + lr;

    #pragma unroll
    for (int s = 0; s < 16; ++s) {
        if (s + 1 < 16) {
            nxt[0] = BLD(s + 1, 0, 0); nxt[1] = BLD(s + 1, 0, 1);
            nxt[2] = BLD(s + 1, 1, 0); nxt[3] = BLD(s + 1, 1, 1);
        }
        f32x4 oa[2][2];
        #pragma unroll
        for (int rf = 0; rf < 2; ++rf)
            #pragma unroll
            for (int ci = 0; ci < 2; ++ci) {
                oa[rf][ci] = (f32x4){0.f, 0.f, 0.f, 0.f};
                oa[rf][ci] = __builtin_amdgcn_mfma_f32_16x16x32_bf16(pa[rf][0], cur[ci * 2 + 0],
                                                                     oa[rf][ci], 0, 0, 0);
                oa[rf][ci] = __builtin_amdgcn_mfma_f32_16x16x32_bf16(pa[rf][1], cur[ci * 2 + 1],
                                                                     oa[rf][ci], 0, 0, 0);
            }
        #pragma unroll
        for (int rf = 0; rf < 2; ++rf)
            #pragma unroll
            for (int ci = 0; ci < 2; ++ci)
                #pragma unroll
                for (int i = 0; i < 4; ++i)
                    op[(size_t)(rf * 16 + i) * DIMY + s * 128 + ci * 16] = oa[rf][ci][i];
        #pragma unroll
        for (int q = 0; q < 4; ++q) cur[q] = nxt[q];
    }
    #undef BLD
}

extern "C" void kernel_launch(void* const* d_in, const int* in_sizes, int n_in,
                              void* d_out, int out_size, void* d_ws, size_t ws_size,
                              hipStream_t stream) {
    const float* x = (const float*)d_in[0];
    const float* w = (const float*)d_in[1];
    const float* b = (const float*)d_in[2];
    const float* R = (const float*)d_in[3];
    float* out = (float*)d_out;

    char* ws = (char*)d_ws;
    unsigned short* wTh = (unsigned short*)ws;                  // 256 KB
    unsigned short* wTl = (unsigned short*)(ws + 262144);       // 256 KB
    unsigned short* RTs = (unsigned short*)(ws + 524288);       // 256 KB

    prep<<<dim3(1024), 256, 0, stream>>>(w, R, wTh, wTl, RTs);
    fused_kernel<<<dim3(BS / GBM), 256, 0, stream>>>(x, wTh, wTl, b, RTs, out);
}